// Round 8
// baseline (125.097 us; speedup 1.0000x reference)
//
#include <hip/hip_runtime.h>
#include <hip/hip_bf16.h>

typedef _Float16 half2v __attribute__((ext_vector_type(2)));
typedef _Float16 half8  __attribute__((ext_vector_type(8)));
typedef __attribute__((ext_vector_type(4))) float floatx4;
typedef __attribute__((ext_vector_type(4))) unsigned int uintx4;

#define GLOBAL_AS __attribute__((address_space(1)))
#define LDS_AS __attribute__((address_space(3)))

// async 16B/lane global->LDS DMA. LDS dest = WAVE-uniform base + lane*16.
__device__ __forceinline__ void async_ld16(const void* g, void* l) {
  __builtin_amdgcn_global_load_lds((const GLOBAL_AS unsigned int*)g,
                                   (LDS_AS unsigned int*)l, 16, 0, 0);
}

__device__ __forceinline__ half2v h2(float v) {
  return (half2v){(_Float16)v, (_Float16)v};
}

// tanh(x) -> f16 Legendre P1..P8 A-fragment for ONE row.
// Packs pairs (P1,P2),(P3,P4),... via packed-f16 math on (t,t) vector.
__device__ __forceinline__ half8 legendre_f16(float xv) {
  float e = __builtin_amdgcn_exp2f(xv * 2.885390081777927f); // 2*log2(e)
  float t0 = 1.0f - 2.0f * __builtin_amdgcn_rcpf(e + 1.0f);
  _Float16 t = (_Float16)t0;
  _Float16 p1 = t;
  _Float16 u2 = t * p1, w2 = u2 - (_Float16)1.0f; _Float16 p2 = (_Float16)(0.5f)      * w2 + u2;
  _Float16 u3 = t * p2, w3 = u3 - p1;             _Float16 p3 = (_Float16)(2.0f/3.0f) * w3 + u3;
  _Float16 u4 = t * p3, w4 = u4 - p2;             _Float16 p4 = (_Float16)(0.75f)     * w4 + u4;
  _Float16 u5 = t * p4, w5 = u5 - p3;             _Float16 p5 = (_Float16)(0.8f)      * w5 + u5;
  _Float16 u6 = t * p5, w6 = u6 - p4;             _Float16 p6 = (_Float16)(5.0f/6.0f) * w6 + u6;
  _Float16 u7 = t * p6, w7 = u7 - p5;             _Float16 p7 = (_Float16)(6.0f/7.0f) * w7 + u7;
  _Float16 u8 = t * p7, w8 = u8 - p6;             _Float16 p8 = (_Float16)(7.0f/8.0f) * w8 + u8;
  return (half8){p1, p2, p3, p4, p5, p6, p7, p8};
}

// ---- kernel 1: c_basis fp32 -> f16, transposed to ws[i][o][d] (256 KB) ----
__global__ void conv_kernel(const float* __restrict__ cb, _Float16* __restrict__ ws) {
  int t = blockIdx.x * 128 + threadIdx.x;   // 0..16383 = (o,i)
  int o = t >> 8;
  int i = t & 255;
  const floatx4* s = (const floatx4*)(cb + ((size_t)o * 256 + i) * 8);
  floatx4 v0 = s[0], v1 = s[1];
  union { _Float16 h[8]; uintx4 u; } w;
  w.h[0] = (_Float16)v0.x; w.h[1] = (_Float16)v0.y;
  w.h[2] = (_Float16)v0.z; w.h[3] = (_Float16)v0.w;
  w.h[4] = (_Float16)v1.x; w.h[5] = (_Float16)v1.y;
  w.h[6] = (_Float16)v1.z; w.h[7] = (_Float16)v1.w;
  *(uintx4*)(ws + (size_t)i * 512 + o * 8) = w.u;
}

// ---- kernel 2: DMA double-buffer, raw s_barrier pair + vmcnt(N>0). ----
// 256 thr (4 waves) over MB=64 rows; wave w owns rows [16w,16w+16) (ONE
// row-group: 1 legendre + 4 MFMA per K-step). Shared B-tile. Grid 1024,
// LDS 40 KB -> 4 blocks/CU = 16 waves/CU = 4 waves/SIMD (2x round 7).
#define MB 64
#define NCH 16

__global__ __launch_bounds__(256, 4) void kan_kernel(
    const float* __restrict__ x, const _Float16* __restrict__ ws,
    const float* __restrict__ bias, float* __restrict__ y) {
  __shared__ __align__(16) _Float16 bt[2][16 * 64 * 8]; // 2 x 16 KB
  __shared__ __align__(16) float xs[2][MB * 16];        // 2 x 4 KB

  const int tid  = threadIdx.x;
  const int wid  = tid >> 6;    // 0..3 = row-group owner
  const int lane = tid & 63;
  const int m    = lane & 15;
  const int q    = lane >> 4;
  const int row_block = blockIdx.x * MB;

  floatx4 acc[4];
#pragma unroll
  for (int nt = 0; nt < 4; ++nt) acc[nt] = (floatx4){0.f, 0.f, 0.f, 0.f};

  // persistent staging pointers (advance per chunk)
  const _Float16* bsrc[4];
#pragma unroll
  for (int t = 0; t < 4; ++t)
    bsrc[t] = ws + (size_t)(t * 256 + wid * 64 + lane) * 8;
  const float* xsrc;
  {
    int slot = wid * 64 + lane;       // 256 slots cover 64 rows x 4 float4
    int r = slot >> 2;
    int c4 = (slot & 3) ^ (r & 3);    // xor swizzle on 16B units
    xsrc = x + (size_t)(row_block + r) * 256 + c4 * 4;
  }

  // 5 DMAs per wave per chunk: 4 B-slots (16 KB total) + 1 x-slot (4 KB)
  auto stage = [&](int buf) {
#pragma unroll
    for (int t = 0; t < 4; ++t) {
      int sb = t * 256 + wid * 64;
      async_ld16(bsrc[t], &bt[buf][sb * 8]);
      bsrc[t] += 8192;
    }
    async_ld16(xsrc, &xs[buf][(wid * 64) * 4]);
    xsrc += 16;
  };

  // x read byte-offset: row_local = wid*16 + m; addr = xoff ^ (ks<<4)
  const int xoff = (wid * 16 + m) * 64 + ((m & 3) << 4) + q * 4;

  stage(0);
#pragma unroll 2
  for (int ch = 0; ch < NCH; ++ch) {
    const int buf = ch & 1;
    // WAR: all waves done computing chunk ch-1 (which read buf^1)
    asm volatile("s_barrier" ::: "memory");
    if (ch + 1 < NCH) {
      stage(buf ^ 1);
      asm volatile("s_waitcnt vmcnt(5)" ::: "memory"); // own chunk-ch DMAs landed
    } else {
      asm volatile("s_waitcnt vmcnt(0)" ::: "memory");
    }
    // RAW: ALL waves' chunk-ch slices landed
    asm volatile("s_barrier" ::: "memory");

    const _Float16* bp = &bt[buf][q * 512 + m * 8];
    const char* xb = (const char*)&xs[buf][0];
#pragma unroll
    for (int ks = 0; ks < 4; ++ks) {
      half8 fb0 = *(const half8*)(bp + ks * 2048 + 0 * 128);
      half8 fb1 = *(const half8*)(bp + ks * 2048 + 1 * 128);
      half8 fb2 = *(const half8*)(bp + ks * 2048 + 2 * 128);
      half8 fb3 = *(const half8*)(bp + ks * 2048 + 3 * 128);
      float xv = *(const float*)(xb + (xoff ^ (ks << 4)));
      half8 fa = legendre_f16(xv);
      acc[0] = __builtin_amdgcn_mfma_f32_16x16x32_f16(fa, fb0, acc[0], 0, 0, 0);
      acc[1] = __builtin_amdgcn_mfma_f32_16x16x32_f16(fa, fb1, acc[1], 0, 0, 0);
      acc[2] = __builtin_amdgcn_mfma_f32_16x16x32_f16(fa, fb2, acc[2], 0, 0, 0);
      acc[3] = __builtin_amdgcn_mfma_f32_16x16x32_f16(fa, fb3, acc[3], 0, 0, 0);
    }
  }

  // epilogue: D[row=(q*4+reg)][col=m], add bias (layout verified R1-R7)
  float bv[4];
#pragma unroll
  for (int nt = 0; nt < 4; ++nt) bv[nt] = bias[nt * 16 + m];
  int gr0 = row_block + wid * 16 + q * 4;
#pragma unroll
  for (int nt = 0; nt < 4; ++nt) {
#pragma unroll
    for (int r = 0; r < 4; ++r) {
      y[(size_t)(gr0 + r) * 64 + nt * 16 + m] = acc[nt][r] + bv[nt];
    }
  }
}

extern "C" void kernel_launch(void* const* d_in, const int* in_sizes, int n_in,
                              void* d_out, int out_size, void* d_ws, size_t ws_size,
                              hipStream_t stream) {
  const float* x    = (const float*)d_in[0];
  const float* cb   = (const float*)d_in[1];
  const float* bias = (const float*)d_in[2];
  float* y = (float*)d_out;
  _Float16* ws = (_Float16*)d_ws;
  int batch = in_sizes[0] / 256;  // 65536
  hipLaunchKernelGGL(conv_kernel, dim3(128), dim3(128), 0, stream, cb, ws);
  hipLaunchKernelGGL(kan_kernel, dim3(batch / MB), dim3(256), 0, stream, x, ws, bias, y);
}